// Round 7
// baseline (38.363 us; speedup 1.0000x reference)
//
#include <hip/hip_runtime.h>

#define NF 39
#define NE 40
#define NB 4096
#define NP 741
#define GST 768               // padded per-sample G row (floats)
#define K1_BLOCKS 1024        // 4 samples/block, 1 per wave
#define K2A_BLOCKS 128
#define K2A_ROWS 32           // 4096 / 128
#define K3_BLOCKS 512         // 8 samples/block, 2 per wave
#define EPS 1.0e-3f

typedef __attribute__((ext_vector_type(8))) short short8;
typedef __attribute__((ext_vector_type(4))) float floatx4;

__device__ __forceinline__ unsigned int f2bf(float f) {
    unsigned int b = __float_as_uint(f);
    b += 0x7FFFu + ((b >> 16) & 1u);   // round-to-nearest-even
    return b >> 16;
}

__device__ __forceinline__ short8 pack8(float4 a, float4 b) {
    union { unsigned int u[4]; short8 s; } o;
    o.u[0] = f2bf(a.x) | (f2bf(a.y) << 16);
    o.u[1] = f2bf(a.z) | (f2bf(a.w) << 16);
    o.u[2] = f2bf(b.x) | (f2bf(b.y) << 16);
    o.u[3] = f2bf(b.z) | (f2bf(b.w) << 16);
    return o.s;
}

// Direct-to-register fragment gather for one sample (validated R4-R6).
__device__ __forceinline__ void load_frags(
    const int* __restrict__ ip, const float* __restrict__ v,
    int rbase, int ehalf, short8 F0[3], short8 F1[3])
{
    const float4 zero4 = {0.f, 0.f, 0.f, 0.f};
#pragma unroll
    for (int I = 0; I < 3; ++I) {
        const int r = rbase + 16 * I;
        const bool vr = (r < NF);
        const int id = vr ? ip[r] : 0;
        const float* vrow = v + (size_t)id * NE;
        const float4 a  = vr ? *reinterpret_cast<const float4*>(vrow + ehalf * 8)     : zero4;
        const float4 bq = vr ? *reinterpret_cast<const float4*>(vrow + ehalf * 8 + 4) : zero4;
        F0[I] = pack8(a, bq);
        const bool v1 = vr && (ehalf == 0);
        const float4 c_ = v1 ? *reinterpret_cast<const float4*>(vrow + 32) : zero4;
        const float4 d_ = v1 ? *reinterpret_cast<const float4*>(vrow + 36) : zero4;
        F1[I] = pack8(c_, d_);
    }
}

__device__ __forceinline__ void gram_mfma(const short8 F0[3], const short8 F1[3], floatx4 acc[6])
{
    acc[0] = __builtin_amdgcn_mfma_f32_16x16x32_bf16(F0[0], F0[0], acc[0], 0, 0, 0);
    acc[1] = __builtin_amdgcn_mfma_f32_16x16x32_bf16(F0[0], F0[1], acc[1], 0, 0, 0);
    acc[2] = __builtin_amdgcn_mfma_f32_16x16x32_bf16(F0[0], F0[2], acc[2], 0, 0, 0);
    acc[3] = __builtin_amdgcn_mfma_f32_16x16x32_bf16(F0[1], F0[1], acc[3], 0, 0, 0);
    acc[4] = __builtin_amdgcn_mfma_f32_16x16x32_bf16(F0[1], F0[2], acc[4], 0, 0, 0);
    acc[5] = __builtin_amdgcn_mfma_f32_16x16x32_bf16(F0[2], F0[2], acc[5], 0, 0, 0);
    acc[0] = __builtin_amdgcn_mfma_f32_16x16x32_bf16(F1[0], F1[0], acc[0], 0, 0, 0);
    acc[1] = __builtin_amdgcn_mfma_f32_16x16x32_bf16(F1[0], F1[1], acc[1], 0, 0, 0);
    acc[2] = __builtin_amdgcn_mfma_f32_16x16x32_bf16(F1[0], F1[2], acc[2], 0, 0, 0);
    acc[3] = __builtin_amdgcn_mfma_f32_16x16x32_bf16(F1[1], F1[1], acc[3], 0, 0, 0);
    acc[4] = __builtin_amdgcn_mfma_f32_16x16x32_bf16(F1[1], F1[2], acc[4], 0, 0, 0);
    acc[5] = __builtin_amdgcn_mfma_f32_16x16x32_bf16(F1[2], F1[2], acc[5], 0, 0, 0);
}

// ---------------- Kernel 1: gather + Gram -> packed-pair f32 G + lsum ----------------
__global__ __launch_bounds__(256) void fm_k1(
    const int* __restrict__ inputs, const float* __restrict__ w,
    const float* __restrict__ v, float* __restrict__ Gp,
    float* __restrict__ lsum)
{
    const int t = threadIdx.x, wid = t >> 6, lane = t & 63;
    const int rbase = lane & 15, ehalf = lane >> 4;
    const int smp = blockIdx.x * 4 + wid;     // one sample per wave

    // per-lane slot -> packed pair index (or -1)
    const int TI[6] = {0, 0, 0, 1, 1, 2};
    const int TJ[6] = {0, 1, 2, 1, 2, 2};
    int pv[6][4];
#pragma unroll
    for (int tl = 0; tl < 6; ++tl)
#pragma unroll
        for (int q = 0; q < 4; ++q) {
            const int gi = 16 * TI[tl] + 4 * ehalf + q;
            const int gj = 16 * TJ[tl] + rbase;
            pv[tl][q] = (gi < gj && gj < NF)
                      ? (38 * gi - (gi * (gi - 1)) / 2 + (gj - gi - 1)) : -1;
        }

    const int* ip = inputs + (size_t)smp * NF;
    short8 F0[3], F1[3];
    load_frags(ip, v, rbase, ehalf, F0, F1);
    floatx4 acc[6] = {};
    gram_mfma(F0, F1, acc);

    // first-order term
    float wv = (lane < NF) ? w[ip[lane]] : 0.0f;
#pragma unroll
    for (int o = 32; o > 0; o >>= 1) wv += __shfl_down(wv, o, 64);
    if (lane == 0) lsum[smp] = wv;

    float* gr = Gp + (size_t)smp * GST;
#pragma unroll
    for (int tl = 0; tl < 6; ++tl)
#pragma unroll
        for (int q = 0; q < 4; ++q)
            if (pv[tl][q] >= 0) gr[pv[tl][q]] = acc[tl][q];
}

// ---------------- Kernel 2a: streaming column partial-reduce (sum, sumsq) ----------------
__global__ __launch_bounds__(256) void fm_k2a(
    const float* __restrict__ Gp, float* __restrict__ partial2)
{
    const int t = threadIdx.x;
    const int r0 = blockIdx.x * K2A_ROWS;
    float s[3] = {}, q[3] = {};
    for (int r = 0; r < K2A_ROWS; ++r) {
        const float* row = Gp + (size_t)(r0 + r) * GST;
#pragma unroll
        for (int c = 0; c < 3; ++c) {
            const float x = row[t + 256 * c];   // cols >= NP are junk; never read downstream
            s[c] += x;
            q[c] = fmaf(x, x, q[c]);
        }
    }
    float* p = partial2 + (size_t)blockIdx.x * 2 * GST;
#pragma unroll
    for (int c = 0; c < 3; ++c) {
        p[t + 256 * c]       = s[c];
        p[GST + t + 256 * c] = q[c];
    }
}

// ---------------- Kernel 2b: finalize mean / scale in pair space ----------------
__global__ __launch_bounds__(256) void fm_k2b(
    const float* __restrict__ partial2, const float* __restrict__ ew,
    float* __restrict__ meanP, float* __restrict__ scaleP)
{
    const int p = blockIdx.x * 256 + threadIdx.x;
    if (p >= NP) return;
    float s1 = 0.f, s2 = 0.f;
#pragma unroll 8
    for (int i = 0; i < K2A_BLOCKS; ++i) {
        const float* pp = partial2 + (size_t)i * 2 * GST;
        s1 += pp[p];
        s2 += pp[GST + p];
    }
    const float m   = s1 * (1.0f / NB);
    const float var = s2 * (1.0f / NB) - m * m;
    meanP[p]  = m;
    scaleP[p] = ew[p] * rsqrtf(var + EPS);
}

// ---------------- Kernel 3: stream G + normalize-reduce + first-order ----------------
__global__ __launch_bounds__(256) void fm_k3(
    const float* __restrict__ Gp, const float* __restrict__ lsum,
    const float* __restrict__ meanP, const float* __restrict__ scaleP,
    const float* __restrict__ bias, float* __restrict__ out)
{
    const int t = threadIdx.x, wid = t >> 6, lane = t & 63;
    const int b0 = blockIdx.x * 8;

    // hoist this lane's 12 mean/scale pairs (cols lane + 64k)
    float mv[12], sv[12];
#pragma unroll
    for (int k = 0; k < 12; ++k) {
        const int p = lane + 64 * k;
        const bool val = (p < NP);
        mv[k] = val ? meanP[p] : 0.0f;
        sv[k] = val ? scaleP[p] : 0.0f;   // scale 0 kills junk cols
    }
    const float bs = bias[0];

#pragma unroll
    for (int s = 0; s < 2; ++s) {
        const int smp = b0 + wid * 2 + s;
        const float* gr = Gp + (size_t)smp * GST;
        float tot = (lane == 0) ? lsum[smp] : 0.0f;
#pragma unroll
        for (int k = 0; k < 12; ++k) {
            const float g = gr[lane + 64 * k];   // in-bounds (GST=768); sv=0 masks junk
            tot += (g - mv[k]) * sv[k];
        }
#pragma unroll
        for (int o = 32; o > 0; o >>= 1) tot += __shfl_down(tot, o, 64);
        if (lane == 0) out[smp] = tot + bs;
    }
}

extern "C" void kernel_launch(void* const* d_in, const int* in_sizes, int n_in,
                              void* d_out, int out_size, void* d_ws, size_t ws_size,
                              hipStream_t stream)
{
    const int*   inputs = (const int*)  d_in[0];
    // d_in[1]=rows, d_in[2]=cols reproduced in-kernel (validated R2-R6)
    const float* w      = (const float*)d_in[3];
    const float* v      = (const float*)d_in[4];
    const float* bias   = (const float*)d_in[5];
    const float* ew     = (const float*)d_in[6];
    float*       out    = (float*)      d_out;

    // ws (floats): Gp[4096*768] | partial2[128*2*768] | meanP[768] | scaleP[768] | lsum[4096]
    float* Gp       = (float*)d_ws;
    float* partial2 = Gp + (size_t)NB * GST;
    float* meanP    = partial2 + (size_t)K2A_BLOCKS * 2 * GST;
    float* scaleP   = meanP + GST;
    float* lsum     = scaleP + GST;

    fm_k1 <<<K1_BLOCKS,  256, 0, stream>>>(inputs, w, v, Gp, lsum);
    fm_k2a<<<K2A_BLOCKS, 256, 0, stream>>>(Gp, partial2);
    fm_k2b<<<3,          256, 0, stream>>>(partial2, ew, meanP, scaleP);
    fm_k3 <<<K3_BLOCKS,  256, 0, stream>>>(Gp, lsum, meanP, scaleP, bias, out);
}

// Round 8
// 34.788 us; speedup vs baseline: 1.1028x; 1.1028x over previous
//
#include <hip/hip_runtime.h>

#define NF 39
#define NE 40
#define NB 4096
#define NSLOT 1536            // 6 tiles * 256 accumulator slots
#define K1_BLOCKS 1024        // 1 sample per wave
#define K2A_BLOCKS 512        // 2 samples per wave
#define K2B_BLOCKS 48
#define K3_BLOCKS 512
#define EPS 1.0e-3f

typedef __attribute__((ext_vector_type(8))) short short8;
typedef __attribute__((ext_vector_type(4))) float floatx4;

__device__ __forceinline__ unsigned int f2bf(float f) {
    unsigned int b = __float_as_uint(f);
    b += 0x7FFFu + ((b >> 16) & 1u);   // round-to-nearest-even
    return b >> 16;
}

__device__ __forceinline__ short8 pack8(float4 a, float4 b) {
    union { unsigned int u[4]; short8 s; } o;
    o.u[0] = f2bf(a.x) | (f2bf(a.y) << 16);
    o.u[1] = f2bf(a.z) | (f2bf(a.w) << 16);
    o.u[2] = f2bf(b.x) | (f2bf(b.y) << 16);
    o.u[3] = f2bf(b.z) | (f2bf(b.w) << 16);
    return o.s;
}

// Direct-to-register fragment gather for one sample (validated R4-R7).
__device__ __forceinline__ void load_frags(
    const int* __restrict__ ip, const float* __restrict__ v,
    int rbase, int ehalf, short8 F0[3], short8 F1[3])
{
    const float4 zero4 = {0.f, 0.f, 0.f, 0.f};
#pragma unroll
    for (int I = 0; I < 3; ++I) {
        const int r = rbase + 16 * I;
        const bool vr = (r < NF);
        const int id = vr ? ip[r] : 0;
        const float* vrow = v + (size_t)id * NE;
        const float4 a  = vr ? *reinterpret_cast<const float4*>(vrow + ehalf * 8)     : zero4;
        const float4 bq = vr ? *reinterpret_cast<const float4*>(vrow + ehalf * 8 + 4) : zero4;
        F0[I] = pack8(a, bq);
        const bool v1 = vr && (ehalf == 0);
        const float4 c_ = v1 ? *reinterpret_cast<const float4*>(vrow + 32) : zero4;
        const float4 d_ = v1 ? *reinterpret_cast<const float4*>(vrow + 36) : zero4;
        F1[I] = pack8(c_, d_);
    }
}

__device__ __forceinline__ void gram_mfma(const short8 F0[3], const short8 F1[3], floatx4 acc[6])
{
    acc[0] = __builtin_amdgcn_mfma_f32_16x16x32_bf16(F0[0], F0[0], acc[0], 0, 0, 0);
    acc[1] = __builtin_amdgcn_mfma_f32_16x16x32_bf16(F0[0], F0[1], acc[1], 0, 0, 0);
    acc[2] = __builtin_amdgcn_mfma_f32_16x16x32_bf16(F0[0], F0[2], acc[2], 0, 0, 0);
    acc[3] = __builtin_amdgcn_mfma_f32_16x16x32_bf16(F0[1], F0[1], acc[3], 0, 0, 0);
    acc[4] = __builtin_amdgcn_mfma_f32_16x16x32_bf16(F0[1], F0[2], acc[4], 0, 0, 0);
    acc[5] = __builtin_amdgcn_mfma_f32_16x16x32_bf16(F0[2], F0[2], acc[5], 0, 0, 0);
    acc[0] = __builtin_amdgcn_mfma_f32_16x16x32_bf16(F1[0], F1[0], acc[0], 0, 0, 0);
    acc[1] = __builtin_amdgcn_mfma_f32_16x16x32_bf16(F1[0], F1[1], acc[1], 0, 0, 0);
    acc[2] = __builtin_amdgcn_mfma_f32_16x16x32_bf16(F1[0], F1[2], acc[2], 0, 0, 0);
    acc[3] = __builtin_amdgcn_mfma_f32_16x16x32_bf16(F1[1], F1[1], acc[3], 0, 0, 0);
    acc[4] = __builtin_amdgcn_mfma_f32_16x16x32_bf16(F1[1], F1[2], acc[4], 0, 0, 0);
    acc[5] = __builtin_amdgcn_mfma_f32_16x16x32_bf16(F1[2], F1[2], acc[5], 0, 0, 0);
}

// ---------------- Kernel 1: PURE gather/repack -> fragment store + lsum ----------------
// No LDS, no MFMA, no stats: max occupancy & MLP for the latency-bound scattered gather.
__global__ __launch_bounds__(256) void fm_k1(
    const int* __restrict__ inputs, const float* __restrict__ w,
    const float* __restrict__ v, short8* __restrict__ wf0,
    short8* __restrict__ wf1, float* __restrict__ lsum)
{
    const int t = threadIdx.x, wid = t >> 6, lane = t & 63;
    const int rbase = lane & 15, ehalf = lane >> 4;
    const int smp = blockIdx.x * 4 + wid;       // one sample per wave

    const int* ip = inputs + (size_t)smp * NF;
    short8 F0[3], F1[3];
    load_frags(ip, v, rbase, ehalf, F0, F1);
#pragma unroll
    for (int I = 0; I < 3; ++I) {
        wf0[((size_t)smp * 3 + I) * 64 + lane] = F0[I];
        if (ehalf == 0) wf1[((size_t)smp * 3 + I) * 16 + rbase] = F1[I];
    }
    float wv = (lane < NF) ? w[ip[lane]] : 0.0f;
#pragma unroll
    for (int o = 32; o > 0; o >>= 1) wv += __shfl_down(wv, o, 64);
    if (lane == 0) lsum[smp] = wv;
}

// ---------------- Kernel 2a: stream frags -> Gram -> block stats fold ----------------
__global__ __launch_bounds__(256) void fm_k2a(
    const short8* __restrict__ wf0, const short8* __restrict__ wf1,
    float* __restrict__ partial)
{
    __shared__ float red[4 * 2 * NSLOT];   // 48 KB cross-wave stats fold
    const int t = threadIdx.x, wid = t >> 6, lane = t & 63;
    const int rbase = lane & 15, ehalf = lane >> 4;
    const int b0 = blockIdx.x * 8;
    const short8 z8 = {0, 0, 0, 0, 0, 0, 0, 0};

    floatx4 sum[6] = {}, sq[6] = {};
#pragma unroll
    for (int s = 0; s < 2; ++s) {
        const int smp = b0 + wid * 2 + s;
        short8 F0[3], F1[3];
#pragma unroll
        for (int I = 0; I < 3; ++I) {
            F0[I] = wf0[((size_t)smp * 3 + I) * 64 + lane];
            F1[I] = (ehalf == 0) ? wf1[((size_t)smp * 3 + I) * 16 + rbase] : z8;
        }
        floatx4 acc[6] = {};
        gram_mfma(F0, F1, acc);
#pragma unroll
        for (int tl = 0; tl < 6; ++tl) {
            sum[tl] += acc[tl];
            sq[tl]  += acc[tl] * acc[tl];
        }
    }
    float* rw = &red[wid * 2 * NSLOT];
#pragma unroll
    for (int tl = 0; tl < 6; ++tl) {
        *reinterpret_cast<floatx4*>(rw + tl * 256 + lane * 4)         = sum[tl];
        *reinterpret_cast<floatx4*>(rw + NSLOT + tl * 256 + lane * 4) = sq[tl];
    }
    __syncthreads();
    float* po = partial + (size_t)blockIdx.x * (2 * NSLOT);
    for (int j = t; j < 2 * NSLOT; j += 256)
        po[j] = red[j] + red[2 * NSLOT + j] + red[4 * NSLOT + j] + red[6 * NSLOT + j];
}

// ---------------- Kernel 2b: fused column-reduce + mean/scale finalize ----------------
__global__ __launch_bounds__(256) void fm_k2b(
    const float* __restrict__ partial, const float* __restrict__ ew,
    float* __restrict__ meanArr, float* __restrict__ scaleArr)
{
    const int t = threadIdx.x;
    const int slotL = t & 31, rg = t >> 5;          // 8 row-groups x 64 rows
    const int slot0 = blockIdx.x * 32;
    float s1 = 0.f, s2 = 0.f;
#pragma unroll 8
    for (int r = 0; r < 64; ++r) {
        const float* row = partial + (size_t)(rg * 64 + r) * (2 * NSLOT);
        s1 += row[slot0 + slotL];
        s2 += row[NSLOT + slot0 + slotL];
    }
    __shared__ float r1[8][32], r2[8][32];
    r1[rg][slotL] = s1;
    r2[rg][slotL] = s2;
    __syncthreads();
    if (t < 32) {
        float a = 0.f, b = 0.f;
#pragma unroll
        for (int g = 0; g < 8; ++g) { a += r1[g][t]; b += r2[g][t]; }
        const int slot = slot0 + t;
        const float m   = a * (1.0f / NB);
        const float var = b * (1.0f / NB) - m * m;
        const int tile = slot >> 8;
        const int l    = (slot & 255) >> 2;
        const int q    = slot & 3;
        const int TI[6] = {0, 0, 0, 1, 1, 2};
        const int TJ[6] = {0, 1, 2, 1, 2, 2};
        const int gi = 16 * TI[tile] + ((l >> 4) << 2) + q;
        const int gj = 16 * TJ[tile] + (l & 15);
        float scl = 0.0f;
        if (gi < gj && gj < NF) {
            const int p = 38 * gi - (gi * (gi - 1)) / 2 + (gj - gi - 1);
            scl = ew[p] * rsqrtf(var + EPS);
        }
        meanArr[slot]  = m;
        scaleArr[slot] = scl;
    }
}

// ---------------- Kernel 3: stream frags + Gram + normalize-reduce ----------------
__global__ __launch_bounds__(256) void fm_k3(
    const short8* __restrict__ wf0, const short8* __restrict__ wf1,
    const float* __restrict__ lsum, const float* __restrict__ meanArr,
    const float* __restrict__ scaleArr, const float* __restrict__ bias,
    float* __restrict__ out)
{
    const int t = threadIdx.x, wid = t >> 6, lane = t & 63;
    const int rbase = lane & 15, ehalf = lane >> 4;
    const int b0 = blockIdx.x * 8;

    floatx4 mf[6], sf[6];
#pragma unroll
    for (int tl = 0; tl < 6; ++tl) {
        mf[tl] = *reinterpret_cast<const floatx4*>(meanArr  + tl * 256 + lane * 4);
        sf[tl] = *reinterpret_cast<const floatx4*>(scaleArr + tl * 256 + lane * 4);
    }
    const float bs = bias[0];
    const short8 z8 = {0, 0, 0, 0, 0, 0, 0, 0};

#pragma unroll
    for (int s = 0; s < 2; ++s) {
        const int smp = b0 + wid * 2 + s;
        short8 F0[3], F1[3];
#pragma unroll
        for (int I = 0; I < 3; ++I) {
            F0[I] = wf0[((size_t)smp * 3 + I) * 64 + lane];
            F1[I] = (ehalf == 0) ? wf1[((size_t)smp * 3 + I) * 16 + rbase] : z8;
        }
        floatx4 acc[6] = {};
        gram_mfma(F0, F1, acc);
        float tot = (lane == 0) ? lsum[smp] : 0.0f;
#pragma unroll
        for (int tl = 0; tl < 6; ++tl)
#pragma unroll
            for (int q = 0; q < 4; ++q)
                tot += (acc[tl][q] - mf[tl][q]) * sf[tl][q];
#pragma unroll
        for (int o = 32; o > 0; o >>= 1) tot += __shfl_down(tot, o, 64);
        if (lane == 0) out[smp] = tot + bs;
    }
}

extern "C" void kernel_launch(void* const* d_in, const int* in_sizes, int n_in,
                              void* d_out, int out_size, void* d_ws, size_t ws_size,
                              hipStream_t stream)
{
    const int*   inputs = (const int*)  d_in[0];
    // d_in[1]=rows, d_in[2]=cols reproduced in-kernel (validated R2-R7)
    const float* w      = (const float*)d_in[3];
    const float* v      = (const float*)d_in[4];
    const float* bias   = (const float*)d_in[5];
    const float* ew     = (const float*)d_in[6];
    float*       out    = (float*)      d_out;

    // ws: wf0[4096*3*64 short8] | wf1[4096*3*16 short8] | floats: partial[512*3072] | mean | scale | lsum
    short8* wf0 = (short8*)d_ws;
    short8* wf1 = wf0 + (size_t)NB * 3 * 64;
    float* partial = (float*)(wf1 + (size_t)NB * 3 * 16);
    float* meanA   = partial + (size_t)K2A_BLOCKS * 2 * NSLOT;
    float* scaleA  = meanA + NSLOT;
    float* lsum    = scaleA + NSLOT;

    fm_k1 <<<K1_BLOCKS,  256, 0, stream>>>(inputs, w, v, wf0, wf1, lsum);
    fm_k2a<<<K2A_BLOCKS, 256, 0, stream>>>(wf0, wf1, partial);
    fm_k2b<<<K2B_BLOCKS, 256, 0, stream>>>(partial, ew, meanA, scaleA);
    fm_k3 <<<K3_BLOCKS,  256, 0, stream>>>(wf0, wf1, lsum, meanA, scaleA, bias, out);
}

// Round 9
// 32.455 us; speedup vs baseline: 1.1821x; 1.0719x over previous
//
#include <hip/hip_runtime.h>

#define NF 39
#define NE 40
#define NB 4096
#define NSLOT 1536            // 6 tiles * 256 accumulator slots
#define NBLK 512
#define SPW 2                 // samples per wave
#define SPB 8                 // samples per block (4 waves * SPW)
#define K2_BLOCKS 48          // 48 * 32 slots = 1536
#define EPS 1.0e-3f

typedef __attribute__((ext_vector_type(8))) short short8;
typedef __attribute__((ext_vector_type(4))) float floatx4;

__device__ __forceinline__ unsigned int f2bf(float f) {
    unsigned int b = __float_as_uint(f);
    b += 0x7FFFu + ((b >> 16) & 1u);   // round-to-nearest-even
    return b >> 16;
}

__device__ __forceinline__ short8 pack8(float4 a, float4 b) {
    union { unsigned int u[4]; short8 s; } o;
    o.u[0] = f2bf(a.x) | (f2bf(a.y) << 16);
    o.u[1] = f2bf(a.z) | (f2bf(a.w) << 16);
    o.u[2] = f2bf(b.x) | (f2bf(b.y) << 16);
    o.u[3] = f2bf(b.z) | (f2bf(b.w) << 16);
    return o.s;
}

// Direct-to-register fragment gather for one sample (validated R4-R8).
__device__ __forceinline__ void load_frags(
    const int* __restrict__ ip, const float* __restrict__ v,
    int rbase, int ehalf, short8 F0[3], short8 F1[3])
{
    const float4 zero4 = {0.f, 0.f, 0.f, 0.f};
#pragma unroll
    for (int I = 0; I < 3; ++I) {
        const int r = rbase + 16 * I;
        const bool vr = (r < NF);
        const int id = vr ? ip[r] : 0;
        const float* vrow = v + (size_t)id * NE;
        const float4 a  = vr ? *reinterpret_cast<const float4*>(vrow + ehalf * 8)     : zero4;
        const float4 bq = vr ? *reinterpret_cast<const float4*>(vrow + ehalf * 8 + 4) : zero4;
        F0[I] = pack8(a, bq);
        const bool v1 = vr && (ehalf == 0);
        const float4 c_ = v1 ? *reinterpret_cast<const float4*>(vrow + 32) : zero4;
        const float4 d_ = v1 ? *reinterpret_cast<const float4*>(vrow + 36) : zero4;
        F1[I] = pack8(c_, d_);
    }
}

__device__ __forceinline__ void gram_mfma(const short8 F0[3], const short8 F1[3], floatx4 acc[6])
{
    acc[0] = __builtin_amdgcn_mfma_f32_16x16x32_bf16(F0[0], F0[0], acc[0], 0, 0, 0);
    acc[1] = __builtin_amdgcn_mfma_f32_16x16x32_bf16(F0[0], F0[1], acc[1], 0, 0, 0);
    acc[2] = __builtin_amdgcn_mfma_f32_16x16x32_bf16(F0[0], F0[2], acc[2], 0, 0, 0);
    acc[3] = __builtin_amdgcn_mfma_f32_16x16x32_bf16(F0[1], F0[1], acc[3], 0, 0, 0);
    acc[4] = __builtin_amdgcn_mfma_f32_16x16x32_bf16(F0[1], F0[2], acc[4], 0, 0, 0);
    acc[5] = __builtin_amdgcn_mfma_f32_16x16x32_bf16(F0[2], F0[2], acc[5], 0, 0, 0);
    acc[0] = __builtin_amdgcn_mfma_f32_16x16x32_bf16(F1[0], F1[0], acc[0], 0, 0, 0);
    acc[1] = __builtin_amdgcn_mfma_f32_16x16x32_bf16(F1[0], F1[1], acc[1], 0, 0, 0);
    acc[2] = __builtin_amdgcn_mfma_f32_16x16x32_bf16(F1[0], F1[2], acc[2], 0, 0, 0);
    acc[3] = __builtin_amdgcn_mfma_f32_16x16x32_bf16(F1[1], F1[1], acc[3], 0, 0, 0);
    acc[4] = __builtin_amdgcn_mfma_f32_16x16x32_bf16(F1[1], F1[2], acc[4], 0, 0, 0);
    acc[5] = __builtin_amdgcn_mfma_f32_16x16x32_bf16(F1[2], F1[2], acc[5], 0, 0, 0);
}

// ---------------- Kernel 1: gather once -> store frags + Gram stats + lsum ----------------
// Two-pass 24 KB LDS fold (sum, then sumsq) -> 6 blocks/CU for gather latency hiding.
__global__ __launch_bounds__(256) void fm_k1(
    const int* __restrict__ inputs, const float* __restrict__ w,
    const float* __restrict__ v, short8* __restrict__ wf0,
    short8* __restrict__ wf1, float* __restrict__ lsum,
    float* __restrict__ partial)
{
    __shared__ float red[4 * NSLOT];   // 24 KB, reused for sum then sumsq
    const int t = threadIdx.x, wid = t >> 6, lane = t & 63;
    const int rbase = lane & 15, ehalf = lane >> 4;
    const int b0 = blockIdx.x * SPB;

    floatx4 sum[6] = {}, sq[6] = {};
#pragma unroll
    for (int s = 0; s < SPW; ++s) {
        const int smp = b0 + wid * SPW + s;
        const int* ip = inputs + (size_t)smp * NF;
        short8 F0[3], F1[3];
        load_frags(ip, v, rbase, ehalf, F0, F1);
        // persist fragments (coalesced): F0 full, F1 only ehalf==0 lanes (rest are zeros)
#pragma unroll
        for (int I = 0; I < 3; ++I) {
            wf0[((size_t)smp * 3 + I) * 64 + lane] = F0[I];
            if (ehalf == 0) wf1[((size_t)smp * 3 + I) * 16 + rbase] = F1[I];
        }
        // first-order term
        float wv = (lane < NF) ? w[ip[lane]] : 0.0f;
#pragma unroll
        for (int o = 32; o > 0; o >>= 1) wv += __shfl_down(wv, o, 64);
        if (lane == 0) lsum[smp] = wv;

        floatx4 acc[6] = {};
        gram_mfma(F0, F1, acc);
#pragma unroll
        for (int tl = 0; tl < 6; ++tl) {
            sum[tl] += acc[tl];
            sq[tl]  += acc[tl] * acc[tl];
        }
    }

    float* po = partial + (size_t)blockIdx.x * (2 * NSLOT);
    float* rw = &red[wid * NSLOT];
    // pass 1: fold sum
#pragma unroll
    for (int tl = 0; tl < 6; ++tl)
        *reinterpret_cast<floatx4*>(rw + tl * 256 + lane * 4) = sum[tl];
    __syncthreads();
    for (int j = t; j < NSLOT; j += 256)
        po[j] = red[j] + red[NSLOT + j] + red[2 * NSLOT + j] + red[3 * NSLOT + j];
    __syncthreads();
    // pass 2: fold sumsq (reuse buffer)
#pragma unroll
    for (int tl = 0; tl < 6; ++tl)
        *reinterpret_cast<floatx4*>(rw + tl * 256 + lane * 4) = sq[tl];
    __syncthreads();
    for (int j = t; j < NSLOT; j += 256)
        po[NSLOT + j] = red[j] + red[NSLOT + j] + red[2 * NSLOT + j] + red[3 * NSLOT + j];
}

// ---------------- Kernel 2: fused column-reduce + mean/scale finalize ----------------
__global__ __launch_bounds__(256) void fm_k2(
    const float* __restrict__ partial, const float* __restrict__ ew,
    float* __restrict__ meanArr, float* __restrict__ scaleArr)
{
    const int t = threadIdx.x;
    const int slotL = t & 31, rg = t >> 5;          // 8 row-groups x 64 rows
    const int slot0 = blockIdx.x * 32;
    float s1 = 0.f, s2 = 0.f;
#pragma unroll 8
    for (int r = 0; r < 64; ++r) {
        const float* row = partial + (size_t)(rg * 64 + r) * (2 * NSLOT);
        s1 += row[slot0 + slotL];
        s2 += row[NSLOT + slot0 + slotL];
    }
    __shared__ float r1[8][32], r2[8][32];
    r1[rg][slotL] = s1;
    r2[rg][slotL] = s2;
    __syncthreads();
    if (t < 32) {
        float a = 0.f, b = 0.f;
#pragma unroll
        for (int g = 0; g < 8; ++g) { a += r1[g][t]; b += r2[g][t]; }
        const int slot = slot0 + t;
        const float m   = a * (1.0f / NB);
        const float var = b * (1.0f / NB) - m * m;
        const int tile = slot >> 8;
        const int l    = (slot & 255) >> 2;
        const int q    = slot & 3;
        const int TI[6] = {0, 0, 0, 1, 1, 2};
        const int TJ[6] = {0, 1, 2, 1, 2, 2};
        const int gi = 16 * TI[tile] + ((l >> 4) << 2) + q;
        const int gj = 16 * TJ[tile] + (l & 15);
        float scl = 0.0f;
        if (gi < gj && gj < NF) {
            const int p = 38 * gi - (gi * (gi - 1)) / 2 + (gj - gi - 1);
            scl = ew[p] * rsqrtf(var + EPS);
        }
        meanArr[slot]  = m;
        scaleArr[slot] = scl;
    }
}

// ---------------- Kernel 3: stream frags + Gram + normalize-reduce ----------------
__global__ __launch_bounds__(256) void fm_k3(
    const short8* __restrict__ wf0, const short8* __restrict__ wf1,
    const float* __restrict__ lsum, const float* __restrict__ meanArr,
    const float* __restrict__ scaleArr, const float* __restrict__ bias,
    float* __restrict__ out)
{
    const int t = threadIdx.x, wid = t >> 6, lane = t & 63;
    const int rbase = lane & 15, ehalf = lane >> 4;
    const int b0 = blockIdx.x * SPB;

    floatx4 mf[6], sf[6];
#pragma unroll
    for (int tl = 0; tl < 6; ++tl) {
        mf[tl] = *reinterpret_cast<const floatx4*>(meanArr  + tl * 256 + lane * 4);
        sf[tl] = *reinterpret_cast<const floatx4*>(scaleArr + tl * 256 + lane * 4);
    }
    const float bs = bias[0];
    const short8 z8 = {0, 0, 0, 0, 0, 0, 0, 0};

#pragma unroll
    for (int s = 0; s < SPW; ++s) {
        const int smp = b0 + wid * SPW + s;
        short8 F0[3], F1[3];
#pragma unroll
        for (int I = 0; I < 3; ++I) {
            F0[I] = wf0[((size_t)smp * 3 + I) * 64 + lane];
            F1[I] = (ehalf == 0) ? wf1[((size_t)smp * 3 + I) * 16 + rbase] : z8;
        }
        floatx4 acc[6] = {};
        gram_mfma(F0, F1, acc);
        float tot = (lane == 0) ? lsum[smp] : 0.0f;
#pragma unroll
        for (int tl = 0; tl < 6; ++tl)
#pragma unroll
            for (int q = 0; q < 4; ++q)
                tot += (acc[tl][q] - mf[tl][q]) * sf[tl][q];
#pragma unroll
        for (int o = 32; o > 0; o >>= 1) tot += __shfl_down(tot, o, 64);
        if (lane == 0) out[smp] = tot + bs;
    }
}

extern "C" void kernel_launch(void* const* d_in, const int* in_sizes, int n_in,
                              void* d_out, int out_size, void* d_ws, size_t ws_size,
                              hipStream_t stream)
{
    const int*   inputs = (const int*)  d_in[0];
    // d_in[1]=rows, d_in[2]=cols reproduced in-kernel (validated R2-R8)
    const float* w      = (const float*)d_in[3];
    const float* v      = (const float*)d_in[4];
    const float* bias   = (const float*)d_in[5];
    const float* ew     = (const float*)d_in[6];
    float*       out    = (float*)      d_out;

    // ws: wf0[4096*3*64 short8] | wf1[4096*3*16 short8] | floats: partial[512*3072] | mean | scale | lsum
    short8* wf0 = (short8*)d_ws;
    short8* wf1 = wf0 + (size_t)NB * 3 * 64;
    float* partial = (float*)(wf1 + (size_t)NB * 3 * 16);
    float* meanA   = partial + (size_t)NBLK * 2 * NSLOT;
    float* scaleA  = meanA + NSLOT;
    float* lsum    = scaleA + NSLOT;

    fm_k1<<<NBLK,      256, 0, stream>>>(inputs, w, v, wf0, wf1, lsum, partial);
    fm_k2<<<K2_BLOCKS, 256, 0, stream>>>(partial, ew, meanA, scaleA);
    fm_k3<<<NBLK,      256, 0, stream>>>(wf0, wf1, lsum, meanA, scaleA, bias, out);
}